// Round 3
// baseline (1385.360 us; speedup 1.0000x reference)
//
#include <hip/hip_runtime.h>
#include <hip/hip_bf16.h>

#define E_DIM 1024
#define HDIM  2730
#define HP    2752   // H padded to multiple of 64
#define NEXP  8
#define NTOK  4096
#define NPAIR 8192
#define LN_EPS 1e-5f

typedef __attribute__((ext_vector_type(8))) short  short8;
typedef __attribute__((ext_vector_type(4))) float  floatx4;
typedef __attribute__((ext_vector_type(4))) int    intx4;

__device__ __forceinline__ __hip_bfloat16 f2bf(float f) { return __float2bfloat16(f); }

// ---------------- router: fp32 logits, top-2, softmax weights ----------------
__global__ __launch_bounds__(256) void router_k(const float* __restrict__ x,
    const float* __restrict__ Wr, int* __restrict__ counts,
    int* __restrict__ tk_idx, float* __restrict__ tk_w) {
  int wid = threadIdx.x >> 6, lane = threadIdx.x & 63;
  int t = blockIdx.x * 4 + wid;
  const float* xr = x + (size_t)t * E_DIM;
  float xv[16];
#pragma unroll
  for (int i = 0; i < 16; ++i) xv[i] = xr[lane + 64 * i];
  float lg[8];
#pragma unroll
  for (int e = 0; e < 8; ++e) {
    const float* wr = Wr + e * E_DIM;
    float a = 0.f;
#pragma unroll
    for (int i = 0; i < 16; ++i) a += xv[i] * wr[lane + 64 * i];
#pragma unroll
    for (int o = 32; o; o >>= 1) a += __shfl_xor(a, o, 64);
    lg[e] = a;
  }
  if (lane == 0) {
    int i0 = 0; float l0 = lg[0];
#pragma unroll
    for (int e = 1; e < 8; ++e) if (lg[e] > l0) { l0 = lg[e]; i0 = e; }
    int i1 = -1; float l1 = -1e30f;
#pragma unroll
    for (int e = 0; e < 8; ++e) if (e != i0 && lg[e] > l1) { l1 = lg[e]; i1 = e; }
    float w0 = 1.f / (1.f + __expf(l1 - l0));
    atomicAdd(&counts[i0], 1);
    atomicAdd(&counts[i1], 1);
    tk_idx[2 * t]     = i0;  tk_idx[2 * t + 1] = i1;
    tk_w[2 * t]       = w0;  tk_w[2 * t + 1]   = 1.f - w0;
  }
}

__global__ void offsets_k(const int* __restrict__ counts, int* __restrict__ offsets,
                          int* __restrict__ cursor) {
  if (threadIdx.x == 0) {
    int off = 0;
    for (int e = 0; e < NEXP; ++e) { offsets[e] = off; cursor[e] = off; off += counts[e]; }
  }
}

__global__ __launch_bounds__(256) void scatter_k(const int* __restrict__ tk_idx,
    const float* __restrict__ tk_w, int* __restrict__ cursor,
    int* __restrict__ pair_token, float* __restrict__ pair_w, int* __restrict__ pair_pos) {
  int t = blockIdx.x * 256 + threadIdx.x;
#pragma unroll
  for (int k = 0; k < 2; ++k) {
    int e = tk_idx[2 * t + k];
    int pos = atomicAdd(&cursor[e], 1);
    pair_token[pos] = t;
    pair_w[pos] = tk_w[2 * t + k];
    pair_pos[2 * t + k] = pos;
  }
}

// ---------------- x -> bf16 ----------------
__global__ __launch_bounds__(256) void xcvt_k(const float* __restrict__ x,
                                              __hip_bfloat16* __restrict__ xb) {
  size_t base = ((size_t)blockIdx.x * 256 + threadIdx.x) * 8;
  const floatx4* src = (const floatx4*)(x + base);
  floatx4 a = src[0], b = src[1];
  union { __hip_bfloat16 h[8]; intx4 v; } u;
#pragma unroll
  for (int j = 0; j < 4; ++j) { u.h[j] = f2bf(a[j]); u.h[4 + j] = f2bf(b[j]); }
  *(intx4*)(xb + base) = u.v;
}

// ------------- transpose + convert: in fp32 [R][C] -> out bf16 [Cp][outRS] -------------
// grid: (Cp/64, outRS/64, NEXP). Reads guarded (r<R, c<C) -> zero padding.
// Writes are 16B/lane (8 r-consecutive bf16 packed per thread).
__global__ __launch_bounds__(256) void tcvt_k(const float* __restrict__ in,
    __hip_bfloat16* __restrict__ out, int R, int C, int outRS,
    size_t inExpStride, size_t outExpStride) {
  __shared__ float tile[64 * 65];
  int e = blockIdx.z;
  const float* ip = in + inExpStride * e;
  __hip_bfloat16* op = out + outExpStride * e;
  int c0 = blockIdx.x * 64, r0 = blockIdx.y * 64;
#pragma unroll
  for (int i = 0; i < 16; ++i) {
    int idx = i * 256 + threadIdx.x;
    int rr = idx >> 6, cc = idx & 63;
    int gr = r0 + rr, gc = c0 + cc;
    tile[rr * 65 + cc] = (gr < R && gc < C) ? ip[(size_t)gr * C + gc] : 0.f;
  }
  __syncthreads();
#pragma unroll
  for (int i = 0; i < 2; ++i) {
    int idx = i * 256 + threadIdx.x;   // 512 chunks of 8
    int cc = idx >> 3, rb = (idx & 7) * 8;
    union { __hip_bfloat16 h[8]; intx4 v; } u;
#pragma unroll
    for (int j = 0; j < 8; ++j) u.h[j] = f2bf(tile[(rb + j) * 65 + cc]);
    *(intx4*)(op + (size_t)(c0 + cc) * outRS + (r0 + rb)) = u.v;
  }
}

// ---------------- GEMM1: h = silu(x@Wv+bv) * (x@Wg+bg), per expert ----------------
// block tile 128(m) x 64(n), BK=32, 4 waves in 2x2; VGPR staging (compiler pipelines
// next tile's global loads under current tile's MFMAs). m-major grid for weight L2 reuse.
__global__ __launch_bounds__(256) void gemm1_k(
    const __hip_bfloat16* __restrict__ xb, const int* __restrict__ pair_token,
    const int* __restrict__ counts, const int* __restrict__ offsets,
    const float* __restrict__ bv, const float* __restrict__ bg,
    const __hip_bfloat16* __restrict__ WvT, const __hip_bfloat16* __restrict__ WgT,
    __hip_bfloat16* __restrict__ h) {
  int e = blockIdx.z;
  int Me = counts[e], off = offsets[e];
  int m0 = blockIdx.x * 128;
  if (m0 >= Me) return;
  int n0 = blockIdx.y * 64;

  __shared__ __hip_bfloat16 sA[128 * 40];
  __shared__ __hip_bfloat16 sBv[64 * 40];
  __shared__ __hip_bfloat16 sBg[64 * 40];
  __shared__ int sTok[128];

  int tid = threadIdx.x;
  if (tid < 128) {
    int m = m0 + tid;
    sTok[tid] = pair_token[off + (m < Me ? m : 0)];
  }
  __syncthreads();

  int wid = tid >> 6, lane = tid & 63;
  int wm = wid >> 1, wn = wid & 1;
  int q = lane >> 4, r = lane & 15;

  // staging coords
  int am = tid >> 1, ak = (tid & 1) * 16;           // A: 128 rows x 2 chunks of 16
  int bn = tid >> 2, bk = (tid & 3) * 8;            // B: 64 rows x 4 chunks of 8
  const __hip_bfloat16* gA = xb + (size_t)sTok[am] * E_DIM + ak;
  size_t bbase = (size_t)e * ((size_t)HP * E_DIM) + (size_t)(n0 + bn) * E_DIM + bk;
  const __hip_bfloat16* gBv = WvT + bbase;
  const __hip_bfloat16* gBg = WgT + bbase;

  floatx4 accv[4][2], accg[4][2];
  floatx4 zz = {0.f, 0.f, 0.f, 0.f};
#pragma unroll
  for (int mi = 0; mi < 4; ++mi)
#pragma unroll
    for (int ni = 0; ni < 2; ++ni) { accv[mi][ni] = zz; accg[mi][ni] = zz; }

  for (int kt = 0; kt < E_DIM / 32; ++kt) {
    int k0 = kt * 32;
    intx4 va0 = *(const intx4*)(gA + k0);
    intx4 va1 = *(const intx4*)(gA + k0 + 8);
    intx4 vbv = *(const intx4*)(gBv + k0);
    intx4 vbg = *(const intx4*)(gBg + k0);
    *(intx4*)(sA + am * 40 + ak) = va0;
    *(intx4*)(sA + am * 40 + ak + 8) = va1;
    *(intx4*)(sBv + bn * 40 + bk) = vbv;
    *(intx4*)(sBg + bn * 40 + bk) = vbg;
    __syncthreads();
    short8 av[4];
#pragma unroll
    for (int mi = 0; mi < 4; ++mi)
      av[mi] = *(const short8*)(sA + (wm * 64 + mi * 16 + r) * 40 + q * 8);
#pragma unroll
    for (int ni = 0; ni < 2; ++ni) {
      short8 b8v = *(const short8*)(sBv + (wn * 32 + ni * 16 + r) * 40 + q * 8);
      short8 b8g = *(const short8*)(sBg + (wn * 32 + ni * 16 + r) * 40 + q * 8);
#pragma unroll
      for (int mi = 0; mi < 4; ++mi) {
        accv[mi][ni] = __builtin_amdgcn_mfma_f32_16x16x32_bf16(av[mi], b8v, accv[mi][ni], 0, 0, 0);
        accg[mi][ni] = __builtin_amdgcn_mfma_f32_16x16x32_bf16(av[mi], b8g, accg[mi][ni], 0, 0, 0);
      }
    }
    __syncthreads();
  }

  // epilogue: bias + SwiGLU, store bf16 h (pad cols n>=HDIM get exact 0)
#pragma unroll
  for (int mi = 0; mi < 4; ++mi) {
#pragma unroll
    for (int rr = 0; rr < 4; ++rr) {
      int m_loc = wm * 64 + mi * 16 + q * 4 + rr;
      int m = m0 + m_loc;
      if (m >= Me) continue;
      size_t hrow = (size_t)(off + m) * HP;
#pragma unroll
      for (int ni = 0; ni < 2; ++ni) {
        int n = n0 + wn * 32 + ni * 16 + r;
        float bvv = (n < HDIM) ? bv[e * HDIM + n] : 0.f;
        float bgv = (n < HDIM) ? bg[e * HDIM + n] : 0.f;
        float hv = accv[mi][ni][rr] + bvv;
        float hg = accg[mi][ni][rr] + bgv;
        float s = 1.f / (1.f + __expf(-hv));
        h[hrow + n] = f2bf(hv * s * hg);
      }
    }
  }
}

// ---------------- GEMM2: pair_out = h @ Wo + bo, per expert ----------------
__global__ __launch_bounds__(256) void gemm2_k(
    const __hip_bfloat16* __restrict__ h,
    const int* __restrict__ counts, const int* __restrict__ offsets,
    const float* __restrict__ bo,
    const __hip_bfloat16* __restrict__ WoT,
    float* __restrict__ pout) {
  int e = blockIdx.z;
  int Me = counts[e], off = offsets[e];
  int m0 = blockIdx.x * 128;
  if (m0 >= Me) return;
  int n0 = blockIdx.y * 64;

  __shared__ __hip_bfloat16 sA[128 * 40];
  __shared__ __hip_bfloat16 sB[64 * 40];

  int tid = threadIdx.x;
  int wid = tid >> 6, lane = tid & 63;
  int wm = wid >> 1, wn = wid & 1;
  int q = lane >> 4, r = lane & 15;

  int am = tid >> 1, ak = (tid & 1) * 16;
  int bn = tid >> 2, bk = (tid & 3) * 8;
  int arow = off + m0 + am;
  if (arow > NPAIR - 1) arow = NPAIR - 1;  // clamp: value unused (m>=Me guarded at store)
  const __hip_bfloat16* gA = h + (size_t)arow * HP + ak;
  const __hip_bfloat16* gB =
      WoT + (size_t)e * ((size_t)E_DIM * HP) + (size_t)(n0 + bn) * HP + bk;

  floatx4 acc[4][2];
  floatx4 zz = {0.f, 0.f, 0.f, 0.f};
#pragma unroll
  for (int mi = 0; mi < 4; ++mi)
#pragma unroll
    for (int ni = 0; ni < 2; ++ni) acc[mi][ni] = zz;

  for (int kt = 0; kt < HP / 32; ++kt) {
    int k0 = kt * 32;
    intx4 va0 = *(const intx4*)(gA + k0);
    intx4 va1 = *(const intx4*)(gA + k0 + 8);
    intx4 vb  = *(const intx4*)(gB + k0);
    *(intx4*)(sA + am * 40 + ak) = va0;
    *(intx4*)(sA + am * 40 + ak + 8) = va1;
    *(intx4*)(sB + bn * 40 + bk) = vb;
    __syncthreads();
    short8 av[4];
#pragma unroll
    for (int mi = 0; mi < 4; ++mi)
      av[mi] = *(const short8*)(sA + (wm * 64 + mi * 16 + r) * 40 + q * 8);
#pragma unroll
    for (int ni = 0; ni < 2; ++ni) {
      short8 b8 = *(const short8*)(sB + (wn * 32 + ni * 16 + r) * 40 + q * 8);
#pragma unroll
      for (int mi = 0; mi < 4; ++mi)
        acc[mi][ni] = __builtin_amdgcn_mfma_f32_16x16x32_bf16(av[mi], b8, acc[mi][ni], 0, 0, 0);
    }
    __syncthreads();
  }

#pragma unroll
  for (int mi = 0; mi < 4; ++mi) {
#pragma unroll
    for (int rr = 0; rr < 4; ++rr) {
      int m_loc = wm * 64 + mi * 16 + q * 4 + rr;
      int m = m0 + m_loc;
      if (m >= Me) continue;
      size_t orow = (size_t)(off + m) * E_DIM;
#pragma unroll
      for (int ni = 0; ni < 2; ++ni) {
        int n = n0 + wn * 32 + ni * 16 + r;
        pout[orow + n] = acc[mi][ni][rr] + bo[e * E_DIM + n];
      }
    }
  }
}

// ---------------- combine + residual + LayerNorm ----------------
__global__ __launch_bounds__(256) void ln_k(const float* __restrict__ x,
    const float* __restrict__ pout, const int* __restrict__ pair_pos,
    const float* __restrict__ pair_w, const float* __restrict__ ln_g,
    const float* __restrict__ ln_b, float* __restrict__ out) {
  int t = blockIdx.x, tid = threadIdx.x;
  int p0 = pair_pos[2 * t], p1 = pair_pos[2 * t + 1];
  float w0 = pair_w[p0], w1 = pair_w[p1];
  const float* xr = x + (size_t)t * E_DIM;
  const float* r0 = pout + (size_t)p0 * E_DIM;
  const float* r1 = pout + (size_t)p1 * E_DIM;
  float y[4];
  float s = 0.f, ss = 0.f;
#pragma unroll
  for (int i = 0; i < 4; ++i) {
    int e = tid + 256 * i;
    y[i] = xr[e] + w0 * r0[e] + w1 * r1[e];
    s += y[i];
    ss += y[i] * y[i];
  }
#pragma unroll
  for (int o = 32; o; o >>= 1) { s += __shfl_xor(s, o, 64); ss += __shfl_xor(ss, o, 64); }
  __shared__ float red[8];
  int wid = tid >> 6, lane = tid & 63;
  if (lane == 0) { red[wid] = s; red[4 + wid] = ss; }
  __syncthreads();
  s  = red[0] + red[1] + red[2] + red[3];
  ss = red[4] + red[5] + red[6] + red[7];
  float mu = s * (1.f / E_DIM);
  float var = ss * (1.f / E_DIM) - mu * mu;
  float rs = rsqrtf(var + LN_EPS);
#pragma unroll
  for (int i = 0; i < 4; ++i) {
    int e = tid + 256 * i;
    out[(size_t)t * E_DIM + e] = ln_g[e] * (y[i] - mu) * rs + ln_b[e];
  }
}

extern "C" void kernel_launch(void* const* d_in, const int* in_sizes, int n_in,
                              void* d_out, int out_size, void* d_ws, size_t ws_size,
                              hipStream_t stream) {
  const float* x    = (const float*)d_in[0];
  const float* Wr   = (const float*)d_in[1];
  const float* Wv   = (const float*)d_in[2];
  const float* bv   = (const float*)d_in[3];
  const float* Wg   = (const float*)d_in[4];
  const float* bg   = (const float*)d_in[5];
  const float* Wo   = (const float*)d_in[6];
  const float* bo   = (const float*)d_in[7];
  const float* ln_g = (const float*)d_in[8];
  const float* ln_b = (const float*)d_in[9];
  float* out = (float*)d_out;

  char* ws = (char*)d_ws;
  size_t off = 0;
  auto alloc = [&](size_t bytes) -> void* {
    void* p = ws + off;
    off = (off + bytes + 255) & ~(size_t)255;
    return p;
  };
  int*   counts     = (int*)alloc(32);
  int*   cursor     = (int*)alloc(32);
  int*   offsets    = (int*)alloc(32);
  int*   tk_idx     = (int*)alloc((size_t)NTOK * 2 * 4);
  float* tk_w       = (float*)alloc((size_t)NTOK * 2 * 4);
  int*   pair_token = (int*)alloc((size_t)NPAIR * 4);
  float* pair_w     = (float*)alloc((size_t)NPAIR * 4);
  int*   pair_pos   = (int*)alloc((size_t)NPAIR * 4);
  __hip_bfloat16* xb   = (__hip_bfloat16*)alloc((size_t)NTOK * E_DIM * 2);
  __hip_bfloat16* hbuf = (__hip_bfloat16*)alloc((size_t)NPAIR * HP * 2);
  float* pout = (float*)alloc((size_t)NPAIR * E_DIM * 4);

  size_t welems = (size_t)NEXP * HP * E_DIM;  // padded transposed weight elements
  __hip_bfloat16* WvT = (__hip_bfloat16*)alloc(welems * 2);
  __hip_bfloat16* WgT = (__hip_bfloat16*)alloc(welems * 2);
  __hip_bfloat16* WoT = (__hip_bfloat16*)alloc(welems * 2);

  hipMemsetAsync(d_ws, 0, 768, stream);  // counts / cursor / offsets

  router_k<<<NTOK / 4, 256, 0, stream>>>(x, Wr, counts, tk_idx, tk_w);
  offsets_k<<<1, 64, 0, stream>>>(counts, offsets, cursor);
  scatter_k<<<NTOK / 256, 256, 0, stream>>>(tk_idx, tk_w, cursor, pair_token, pair_w, pair_pos);
  xcvt_k<<<(NTOK * E_DIM) / (256 * 8), 256, 0, stream>>>(x, xb);

  // Wv,Wg: fp32 [1024][2730] -> bf16 [2752][1024]
  tcvt_k<<<dim3(HP / 64, E_DIM / 64, NEXP), 256, 0, stream>>>(
      Wv, WvT, E_DIM, HDIM, E_DIM, (size_t)E_DIM * HDIM, (size_t)HP * E_DIM);
  tcvt_k<<<dim3(HP / 64, E_DIM / 64, NEXP), 256, 0, stream>>>(
      Wg, WgT, E_DIM, HDIM, E_DIM, (size_t)E_DIM * HDIM, (size_t)HP * E_DIM);
  // Wo: fp32 [2730][1024] -> bf16 [1024][2752]
  tcvt_k<<<dim3(E_DIM / 64, HP / 64, NEXP), 256, 0, stream>>>(
      Wo, WoT, HDIM, E_DIM, HP, (size_t)HDIM * E_DIM, (size_t)E_DIM * HP);

  gemm1_k<<<dim3(32, HP / 64, NEXP), 256, 0, stream>>>(
      xb, pair_token, counts, offsets, bv, bg, WvT, WgT, hbuf);
  gemm2_k<<<dim3(32, E_DIM / 64, NEXP), 256, 0, stream>>>(
      hbuf, counts, offsets, bo, WoT, pout);

  ln_k<<<NTOK, 256, 0, stream>>>(x, pout, pair_pos, pair_w, ln_g, ln_b, out);
}

// Round 4
// 733.171 us; speedup vs baseline: 1.8895x; 1.8895x over previous
//
#include <hip/hip_runtime.h>
#include <hip/hip_bf16.h>

#define E_DIM 1024
#define HDIM  2730
#define HP    2752   // H padded to multiple of 64
#define NEXP  8
#define NTOK  4096
#define NPAIR 8192
#define NSLOT 72     // max m-tiles of 128 over all experts (<=71) + pad
#define LN_EPS 1e-5f

typedef __attribute__((ext_vector_type(8))) short  short8;
typedef __attribute__((ext_vector_type(4))) short  short4v;
typedef __attribute__((ext_vector_type(4))) float  floatx4;
typedef __attribute__((ext_vector_type(4))) int    intx4;

__device__ __forceinline__ __hip_bfloat16 f2bf(float f) { return __float2bfloat16(f); }

// ---------------- router: fp32 logits, top-2, softmax weights ----------------
__global__ __launch_bounds__(256) void router_k(const float* __restrict__ x,
    const float* __restrict__ Wr, int* __restrict__ counts,
    int* __restrict__ tk_idx, float* __restrict__ tk_w) {
  int wid = threadIdx.x >> 6, lane = threadIdx.x & 63;
  int t = blockIdx.x * 4 + wid;
  const float* xr = x + (size_t)t * E_DIM;
  float xv[16];
#pragma unroll
  for (int i = 0; i < 16; ++i) xv[i] = xr[lane + 64 * i];
  float lg[8];
#pragma unroll
  for (int e = 0; e < 8; ++e) {
    const float* wr = Wr + e * E_DIM;
    float a = 0.f;
#pragma unroll
    for (int i = 0; i < 16; ++i) a += xv[i] * wr[lane + 64 * i];
#pragma unroll
    for (int o = 32; o; o >>= 1) a += __shfl_xor(a, o, 64);
    lg[e] = a;
  }
  if (lane == 0) {
    int i0 = 0; float l0 = lg[0];
#pragma unroll
    for (int e = 1; e < 8; ++e) if (lg[e] > l0) { l0 = lg[e]; i0 = e; }
    int i1 = -1; float l1 = -1e30f;
#pragma unroll
    for (int e = 0; e < 8; ++e) if (e != i0 && lg[e] > l1) { l1 = lg[e]; i1 = e; }
    float w0 = 1.f / (1.f + __expf(l1 - l0));
    atomicAdd(&counts[i0], 1);
    atomicAdd(&counts[i1], 1);
    tk_idx[2 * t]     = i0;  tk_idx[2 * t + 1] = i1;
    tk_w[2 * t]       = w0;  tk_w[2 * t + 1]   = 1.f - w0;
  }
}

// offsets + compact (expert, m0) tile table: active slots contiguous from 0.
__global__ void offsets_k(const int* __restrict__ counts, int* __restrict__ offsets,
                          int* __restrict__ cursor,
                          int* __restrict__ slot_e, int* __restrict__ slot_m0) {
  if (threadIdx.x == 0) {
    int off = 0, s = 0;
    for (int e = 0; e < NEXP; ++e) {
      offsets[e] = off; cursor[e] = off;
      for (int m0 = 0; m0 < counts[e]; m0 += 128) { slot_e[s] = e; slot_m0[s] = m0; ++s; }
      off += counts[e];
    }
    for (; s < NSLOT; ++s) { slot_e[s] = -1; slot_m0[s] = 0; }
  }
}

__global__ __launch_bounds__(256) void scatter_k(const int* __restrict__ tk_idx,
    const float* __restrict__ tk_w, int* __restrict__ cursor,
    int* __restrict__ pair_token, float* __restrict__ pair_w, int* __restrict__ pair_pos) {
  int t = blockIdx.x * 256 + threadIdx.x;
#pragma unroll
  for (int k = 0; k < 2; ++k) {
    int e = tk_idx[2 * t + k];
    int pos = atomicAdd(&cursor[e], 1);
    pair_token[pos] = t;
    pair_w[pos] = tk_w[2 * t + k];
    pair_pos[2 * t + k] = pos;
  }
}

// ---------------- expert-sorted token rows: xs[p] = bf16(x[pair_token[p]]) ----------------
__global__ __launch_bounds__(256) void gatherx_k(const float* __restrict__ x,
    const int* __restrict__ pair_token, __hip_bfloat16* __restrict__ xs) {
  int p = blockIdx.x;
  int t = pair_token[p];
  const float* src = x + (size_t)t * E_DIM;
  __hip_bfloat16* dst = xs + (size_t)p * E_DIM;
  int i = threadIdx.x * 4;
  floatx4 v = *(const floatx4*)(src + i);
  union { __hip_bfloat16 h[4]; short4v s; } u;
#pragma unroll
  for (int j = 0; j < 4; ++j) u.h[j] = f2bf(v[j]);
  *(short4v*)(dst + i) = u.s;
}

// ------------- transpose + convert: in fp32 [R][C] -> out bf16 [Cp][outRS] -------------
__global__ __launch_bounds__(256) void tcvt_k(const float* __restrict__ in,
    __hip_bfloat16* __restrict__ out, int R, int C, int outRS,
    size_t inExpStride, size_t outExpStride) {
  __shared__ float tile[64 * 65];
  int e = blockIdx.z;
  const float* ip = in + inExpStride * e;
  __hip_bfloat16* op = out + outExpStride * e;
  int c0 = blockIdx.x * 64, r0 = blockIdx.y * 64;
#pragma unroll
  for (int i = 0; i < 16; ++i) {
    int idx = i * 256 + threadIdx.x;
    int rr = idx >> 6, cc = idx & 63;
    int gr = r0 + rr, gc = c0 + cc;
    tile[rr * 65 + cc] = (gr < R && gc < C) ? ip[(size_t)gr * C + gc] : 0.f;
  }
  __syncthreads();
#pragma unroll
  for (int i = 0; i < 2; ++i) {
    int idx = i * 256 + threadIdx.x;
    int cc = idx >> 3, rb = (idx & 7) * 8;
    union { __hip_bfloat16 h[8]; intx4 v; } u;
#pragma unroll
    for (int j = 0; j < 8; ++j) u.h[j] = f2bf(tile[(rb + j) * 65 + cc]);
    *(intx4*)(op + (size_t)(c0 + cc) * outRS + (r0 + rb)) = u.v;
  }
}

// ---------------- GEMM1: h = silu(xs@Wv+bv) * (xs@Wg+bg) ----------------
// 128m x 64n block, BK=64 as two stride-40 subtiles; grid (n-tiles, slot).
__global__ __launch_bounds__(256) void gemm1_k(
    const __hip_bfloat16* __restrict__ xs,
    const int* __restrict__ counts, const int* __restrict__ offsets,
    const int* __restrict__ slot_e, const int* __restrict__ slot_m0,
    const float* __restrict__ bv, const float* __restrict__ bg,
    const __hip_bfloat16* __restrict__ WvT, const __hip_bfloat16* __restrict__ WgT,
    __hip_bfloat16* __restrict__ h) {
  int slot = blockIdx.y;
  int e = slot_e[slot];
  if (e < 0) return;
  int m0 = slot_m0[slot];
  int Me = counts[e], off = offsets[e];
  int n0 = blockIdx.x * 64;

  __shared__ __hip_bfloat16 sA[2 * 128 * 40];
  __shared__ __hip_bfloat16 sBv[2 * 64 * 40];
  __shared__ __hip_bfloat16 sBg[2 * 64 * 40];

  int tid = threadIdx.x;
  int wid = tid >> 6, lane = tid & 63;
  int wm = wid >> 1, wn = wid & 1;
  int q = lane >> 4, r = lane & 15;

  // staging: 8 lanes/row, 16B each -> 128B contiguous per row
  int srow = tid >> 3;          // 0..31
  int kk   = (tid & 7) * 8;     // 0..56
  int ks   = kk >> 5, k2 = kk & 31;
  const __hip_bfloat16* gA  = xs + (size_t)(off + m0 + srow) * E_DIM + kk;
  size_t bb = (size_t)e * ((size_t)HP * E_DIM) + (size_t)(n0 + srow) * E_DIM + kk;
  const __hip_bfloat16* gBv = WvT + bb;
  const __hip_bfloat16* gBg = WgT + bb;
  __hip_bfloat16* wA  = sA  + ks * (128 * 40) + srow * 40 + k2;
  __hip_bfloat16* wBv = sBv + ks * (64 * 40) + srow * 40 + k2;
  __hip_bfloat16* wBg = sBg + ks * (64 * 40) + srow * 40 + k2;

  floatx4 accv[4][2], accg[4][2];
  floatx4 zz = {0.f, 0.f, 0.f, 0.f};
#pragma unroll
  for (int mi = 0; mi < 4; ++mi)
#pragma unroll
    for (int ni = 0; ni < 2; ++ni) { accv[mi][ni] = zz; accg[mi][ni] = zz; }

  for (int kt = 0; kt < E_DIM / 64; ++kt) {
    size_t ko = (size_t)kt * 64;
#pragma unroll
    for (int i = 0; i < 4; ++i)
      *(intx4*)(wA + i * 32 * 40) = *(const intx4*)(gA + ko + (size_t)i * 32 * E_DIM);
#pragma unroll
    for (int i = 0; i < 2; ++i) {
      *(intx4*)(wBv + i * 32 * 40) = *(const intx4*)(gBv + ko + (size_t)i * 32 * E_DIM);
      *(intx4*)(wBg + i * 32 * 40) = *(const intx4*)(gBg + ko + (size_t)i * 32 * E_DIM);
    }
    __syncthreads();
#pragma unroll
    for (int s = 0; s < 2; ++s) {
      const __hip_bfloat16* pA  = sA  + s * (128 * 40);
      const __hip_bfloat16* pBv = sBv + s * (64 * 40);
      const __hip_bfloat16* pBg = sBg + s * (64 * 40);
      short8 av[4];
#pragma unroll
      for (int mi = 0; mi < 4; ++mi)
        av[mi] = *(const short8*)(pA + (wm * 64 + mi * 16 + r) * 40 + q * 8);
#pragma unroll
      for (int ni = 0; ni < 2; ++ni) {
        short8 b8v = *(const short8*)(pBv + (wn * 32 + ni * 16 + r) * 40 + q * 8);
        short8 b8g = *(const short8*)(pBg + (wn * 32 + ni * 16 + r) * 40 + q * 8);
#pragma unroll
        for (int mi = 0; mi < 4; ++mi) {
          accv[mi][ni] = __builtin_amdgcn_mfma_f32_16x16x32_bf16(av[mi], b8v, accv[mi][ni], 0, 0, 0);
          accg[mi][ni] = __builtin_amdgcn_mfma_f32_16x16x32_bf16(av[mi], b8g, accg[mi][ni], 0, 0, 0);
        }
      }
    }
    __syncthreads();
  }

#pragma unroll
  for (int mi = 0; mi < 4; ++mi) {
#pragma unroll
    for (int rr = 0; rr < 4; ++rr) {
      int m_loc = wm * 64 + mi * 16 + q * 4 + rr;
      int m = m0 + m_loc;
      if (m >= Me) continue;
      size_t hrow = (size_t)(off + m) * HP;
#pragma unroll
      for (int ni = 0; ni < 2; ++ni) {
        int n = n0 + wn * 32 + ni * 16 + r;
        float bvv = (n < HDIM) ? bv[e * HDIM + n] : 0.f;
        float bgv = (n < HDIM) ? bg[e * HDIM + n] : 0.f;
        float hv = accv[mi][ni][rr] + bvv;
        float hg = accg[mi][ni][rr] + bgv;
        float sgm = 1.f / (1.f + __expf(-hv));
        h[hrow + n] = f2bf(hv * sgm * hg);
      }
    }
  }
}

// ---------------- GEMM2: pair_out = h @ Wo + bo ----------------
__global__ __launch_bounds__(256) void gemm2_k(
    const __hip_bfloat16* __restrict__ hb,
    const int* __restrict__ counts, const int* __restrict__ offsets,
    const int* __restrict__ slot_e, const int* __restrict__ slot_m0,
    const float* __restrict__ bo,
    const __hip_bfloat16* __restrict__ WoT,
    float* __restrict__ pout) {
  int slot = blockIdx.y;
  int e = slot_e[slot];
  if (e < 0) return;
  int m0 = slot_m0[slot];
  int Me = counts[e], off = offsets[e];
  int n0 = blockIdx.x * 64;

  __shared__ __hip_bfloat16 sA[2 * 128 * 40];
  __shared__ __hip_bfloat16 sB[2 * 64 * 40];

  int tid = threadIdx.x;
  int wid = tid >> 6, lane = tid & 63;
  int wm = wid >> 1, wn = wid & 1;
  int q = lane >> 4, r = lane & 15;

  int srow = tid >> 3;
  int kk   = (tid & 7) * 8;
  int ks   = kk >> 5, k2 = kk & 31;
  const __hip_bfloat16* gA = hb + (size_t)(off + m0 + srow) * HP + kk;
  const __hip_bfloat16* gB =
      WoT + (size_t)e * ((size_t)E_DIM * HP) + (size_t)(n0 + srow) * HP + kk;
  __hip_bfloat16* wA = sA + ks * (128 * 40) + srow * 40 + k2;
  __hip_bfloat16* wB = sB + ks * (64 * 40) + srow * 40 + k2;

  floatx4 acc[4][2];
  floatx4 zz = {0.f, 0.f, 0.f, 0.f};
#pragma unroll
  for (int mi = 0; mi < 4; ++mi)
#pragma unroll
    for (int ni = 0; ni < 2; ++ni) acc[mi][ni] = zz;

  for (int kt = 0; kt < HP / 64; ++kt) {
    size_t ko = (size_t)kt * 64;
#pragma unroll
    for (int i = 0; i < 4; ++i)
      *(intx4*)(wA + i * 32 * 40) = *(const intx4*)(gA + ko + (size_t)i * 32 * HP);
#pragma unroll
    for (int i = 0; i < 2; ++i)
      *(intx4*)(wB + i * 32 * 40) = *(const intx4*)(gB + ko + (size_t)i * 32 * HP);
    __syncthreads();
#pragma unroll
    for (int s = 0; s < 2; ++s) {
      const __hip_bfloat16* pA = sA + s * (128 * 40);
      const __hip_bfloat16* pB = sB + s * (64 * 40);
      short8 av[4];
#pragma unroll
      for (int mi = 0; mi < 4; ++mi)
        av[mi] = *(const short8*)(pA + (wm * 64 + mi * 16 + r) * 40 + q * 8);
#pragma unroll
      for (int ni = 0; ni < 2; ++ni) {
        short8 b8 = *(const short8*)(pB + (wn * 32 + ni * 16 + r) * 40 + q * 8);
#pragma unroll
        for (int mi = 0; mi < 4; ++mi)
          acc[mi][ni] = __builtin_amdgcn_mfma_f32_16x16x32_bf16(av[mi], b8, acc[mi][ni], 0, 0, 0);
      }
    }
    __syncthreads();
  }

#pragma unroll
  for (int mi = 0; mi < 4; ++mi) {
#pragma unroll
    for (int rr = 0; rr < 4; ++rr) {
      int m_loc = wm * 64 + mi * 16 + q * 4 + rr;
      int m = m0 + m_loc;
      if (m >= Me) continue;
      size_t orow = (size_t)(off + m) * E_DIM;
#pragma unroll
      for (int ni = 0; ni < 2; ++ni) {
        int n = n0 + wn * 32 + ni * 16 + r;
        pout[orow + n] = acc[mi][ni][rr] + bo[e * E_DIM + n];
      }
    }
  }
}

// ---------------- combine + residual + LayerNorm ----------------
__global__ __launch_bounds__(256) void ln_k(const float* __restrict__ x,
    const float* __restrict__ pout, const int* __restrict__ pair_pos,
    const float* __restrict__ pair_w, const float* __restrict__ ln_g,
    const float* __restrict__ ln_b, float* __restrict__ out) {
  int t = blockIdx.x, tid = threadIdx.x;
  int p0 = pair_pos[2 * t], p1 = pair_pos[2 * t + 1];
  float w0 = pair_w[p0], w1 = pair_w[p1];
  const float* xr = x + (size_t)t * E_DIM;
  const float* r0 = pout + (size_t)p0 * E_DIM;
  const float* r1 = pout + (size_t)p1 * E_DIM;
  float y[4];
  float s = 0.f, ss = 0.f;
#pragma unroll
  for (int i = 0; i < 4; ++i) {
    int e = tid + 256 * i;
    y[i] = xr[e] + w0 * r0[e] + w1 * r1[e];
    s += y[i];
    ss += y[i] * y[i];
  }
#pragma unroll
  for (int o = 32; o; o >>= 1) { s += __shfl_xor(s, o, 64); ss += __shfl_xor(ss, o, 64); }
  __shared__ float red[8];
  int wid = tid >> 6, lane = tid & 63;
  if (lane == 0) { red[wid] = s; red[4 + wid] = ss; }
  __syncthreads();
  s  = red[0] + red[1] + red[2] + red[3];
  ss = red[4] + red[5] + red[6] + red[7];
  float mu = s * (1.f / E_DIM);
  float var = ss * (1.f / E_DIM) - mu * mu;
  float rs = rsqrtf(var + LN_EPS);
#pragma unroll
  for (int i = 0; i < 4; ++i) {
    int e = tid + 256 * i;
    out[(size_t)t * E_DIM + e] = ln_g[e] * (y[i] - mu) * rs + ln_b[e];
  }
}

extern "C" void kernel_launch(void* const* d_in, const int* in_sizes, int n_in,
                              void* d_out, int out_size, void* d_ws, size_t ws_size,
                              hipStream_t stream) {
  const float* x    = (const float*)d_in[0];
  const float* Wr   = (const float*)d_in[1];
  const float* Wv   = (const float*)d_in[2];
  const float* bv   = (const float*)d_in[3];
  const float* Wg   = (const float*)d_in[4];
  const float* bg   = (const float*)d_in[5];
  const float* Wo   = (const float*)d_in[6];
  const float* bo   = (const float*)d_in[7];
  const float* ln_g = (const float*)d_in[8];
  const float* ln_b = (const float*)d_in[9];
  float* out = (float*)d_out;

  char* ws = (char*)d_ws;
  size_t off = 0;
  auto alloc = [&](size_t bytes) -> void* {
    void* p = ws + off;
    off = (off + bytes + 255) & ~(size_t)255;
    return p;
  };
  int*   counts     = (int*)alloc(32);
  int*   cursor     = (int*)alloc(32);
  int*   offsets    = (int*)alloc(32);
  int*   slot_e     = (int*)alloc(NSLOT * 4);
  int*   slot_m0    = (int*)alloc(NSLOT * 4);
  int*   tk_idx     = (int*)alloc((size_t)NTOK * 2 * 4);
  float* tk_w       = (float*)alloc((size_t)NTOK * 2 * 4);
  int*   pair_token = (int*)alloc((size_t)NPAIR * 4);
  float* pair_w     = (float*)alloc((size_t)NPAIR * 4);
  int*   pair_pos   = (int*)alloc((size_t)NPAIR * 4);
  __hip_bfloat16* xs   = (__hip_bfloat16*)alloc((size_t)(NPAIR + 128) * E_DIM * 2);
  __hip_bfloat16* hbuf = (__hip_bfloat16*)alloc((size_t)(NPAIR + 128) * HP * 2);
  float* pout = (float*)alloc((size_t)NPAIR * E_DIM * 4);

  size_t welems = (size_t)NEXP * HP * E_DIM;
  __hip_bfloat16* WvT = (__hip_bfloat16*)alloc(welems * 2);
  __hip_bfloat16* WgT = (__hip_bfloat16*)alloc(welems * 2);
  __hip_bfloat16* WoT = (__hip_bfloat16*)alloc(welems * 2);

  hipMemsetAsync(d_ws, 0, 1024, stream);  // counts / cursor / offsets / slots

  router_k<<<NTOK / 4, 256, 0, stream>>>(x, Wr, counts, tk_idx, tk_w);
  offsets_k<<<1, 64, 0, stream>>>(counts, offsets, cursor, slot_e, slot_m0);
  scatter_k<<<NTOK / 256, 256, 0, stream>>>(tk_idx, tk_w, cursor, pair_token, pair_w, pair_pos);
  gatherx_k<<<NPAIR, 256, 0, stream>>>(x, pair_token, xs);

  tcvt_k<<<dim3(HP / 64, E_DIM / 64, NEXP), 256, 0, stream>>>(
      Wv, WvT, E_DIM, HDIM, E_DIM, (size_t)E_DIM * HDIM, (size_t)HP * E_DIM);
  tcvt_k<<<dim3(HP / 64, E_DIM / 64, NEXP), 256, 0, stream>>>(
      Wg, WgT, E_DIM, HDIM, E_DIM, (size_t)E_DIM * HDIM, (size_t)HP * E_DIM);
  tcvt_k<<<dim3(E_DIM / 64, HP / 64, NEXP), 256, 0, stream>>>(
      Wo, WoT, HDIM, E_DIM, HP, (size_t)HDIM * E_DIM, (size_t)E_DIM * HP);

  gemm1_k<<<dim3(HP / 64, NSLOT), 256, 0, stream>>>(
      xs, counts, offsets, slot_e, slot_m0, bv, bg, WvT, WgT, hbuf);
  gemm2_k<<<dim3(E_DIM / 64, NSLOT), 256, 0, stream>>>(
      hbuf, counts, offsets, slot_e, slot_m0, bo, WoT, pout);

  ln_k<<<NTOK, 256, 0, stream>>>(x, pout, pair_pos, pair_w, ln_g, ln_b, out);
}